// Round 13
// baseline (379.804 us; speedup 1.0000x reference)
//
#include <hip/hip_runtime.h>
#include <hip/hip_bf16.h>

#define DI __device__ __forceinline__

typedef __attribute__((ext_vector_type(8))) short short8;   // 8 bf16 (4 VGPR)
typedef __attribute__((ext_vector_type(4))) short short4v;  // 4 bf16 (8B)
typedef __attribute__((ext_vector_type(4))) float floatx4;

constexpr int NN = 50000;
constexpr int NE = 500000;
constexpr int H  = 128;
constexpr int NB1 = (NN + 255) / 256;   // scan blocks

// ---- ws layout (bytes) ----
constexpr size_t OFF_BF   = 262144;
constexpr size_t OFF_PS   = 327680;
constexpr size_t OFF_PR   = 13127680;
constexpr size_t OFF_CNT  = 25927680;
constexpr size_t OFF_TMP  = 26127680;
constexpr size_t OFF_RS   = 26327680;
constexpr size_t OFF_CUR  = 26527680;
constexpr size_t OFF_BSUM = 26727680;
constexpr size_t OFF_CSR  = 26728704;

constexpr int WF_TOTAL = 131072;      // 8*16384 shorts
constexpr int BIASF_FLOATS = 8*2048;
constexpr int PREP_TOTAL = WF_TOTAL + BIASF_FLOATS + NN;   // + zero_cnt fold

DI short f2bf(float f){ __bf16 b = (__bf16)f; return __builtin_bit_cast(short, b); }
DI float bf2f(short s){ return __builtin_bit_cast(float, ((unsigned)(unsigned short)s) << 16); }

// Weight frags. Standard blocks: t=((ks*8+nt)*64+l)*8+j <-> W[roff+32ks+8(l>>4)+j][16nt+(l&15)]
// Block 7 (phase2-B map): row = 32ks + 16*(j>>2) + 4*(l>>4) + (j&3). Tail range zeroes cnt.
__global__ __launch_bounds__(256) void prep_kernel(
    const float* __restrict__ We1, const float* __restrict__ We2,
    const float* __restrict__ Wn1, const float* __restrict__ Wn2,
    const float* __restrict__ be1, const float* __restrict__ be2,
    const float* __restrict__ ge,  const float* __restrict__ bge,
    const float* __restrict__ bn1, const float* __restrict__ bn2,
    const float* __restrict__ gn,  const float* __restrict__ bgn,
    short* __restrict__ wf, float* __restrict__ bf, int* __restrict__ cnt)
{
  int t = blockIdx.x*256 + threadIdx.x;
  if (t < WF_TOTAL) {
    int blk = t >> 14, u = t & 16383;
    int j = u & 7, l = (u>>3)&63, nt = (u>>9)&7, ks = u>>12;
    const float* src; int roff; bool blayout = false;
    switch (blk) {
      case 0: src = We1; roff = 0;   break;
      case 1: src = We1; roff = 128; break;
      case 2: src = We1; roff = 256; break;
      case 3: src = We2; roff = 0;   break;
      case 4: src = Wn1; roff = 0;   break;
      case 5: src = Wn1; roff = 128; break;
      case 6: src = Wn2; roff = 0;   break;
      default: src = We2; roff = 0; blayout = true; break;
    }
    int row = blayout ? (32*ks + 16*(j>>2) + 4*(l>>4) + (j&3))
                      : (roff + 32*ks + 8*(l>>4) + j);
    int col = 16*nt + (l&15);
    wf[t] = f2bf(src[row*H + col]);
  } else if (t < WF_TOTAL + BIASF_FLOATS) {
    int tb = t - WF_TOTAL;
    int arr = tb >> 11, u = tb & 2047;
    int r = u&3, l = (u>>2)&63, mt = u>>8;
    int feat = 16*mt + 4*(l>>4) + r;
    const float* s;
    switch (arr) {
      case 0: s = be1; break; case 1: s = be2; break;
      case 2: s = ge;  break; case 3: s = bge; break;
      case 4: s = bn1; break; case 5: s = bn2; break;
      case 6: s = gn;  break; default: s = bgn; break;
    }
    bf[tb] = s[feat];
  } else if (t < PREP_TOTAL) {
    cnt[t - WF_TOTAL - BIASF_FLOATS] = 0;
  }
}

// ---------- CSR build ----------
__global__ __launch_bounds__(256) void hist_kernel(const int* __restrict__ ei, int* __restrict__ cnt){
  int e = blockIdx.x*256 + threadIdx.x;
  if (e < NE) atomicAdd(&cnt[ei[2*e+1]], 1);
}

__global__ __launch_bounds__(256) void scan1_kernel(const int* __restrict__ cnt,
                                                    int* __restrict__ tmp, int* __restrict__ blocksum){
  __shared__ int s[256];
  int t = threadIdx.x, i = blockIdx.x*256 + t;
  int v = (i < NN) ? cnt[i] : 0;
  s[t] = v; __syncthreads();
#pragma unroll
  for (int o=1; o<256; o<<=1){
    int u = (t >= o) ? s[t-o] : 0;
    __syncthreads();
    s[t] += u;
    __syncthreads();
  }
  if (i < NN) tmp[i] = s[t];
  if (t == 255) blocksum[blockIdx.x] = s[255];
}

// scan2 folded in: every block computes its own exclusive prefix over blocksum[0..bid)
__global__ __launch_bounds__(256) void scan3_kernel(const int* __restrict__ cnt, const int* __restrict__ tmp,
                                                    const int* __restrict__ blocksum,
                                                    int* __restrict__ rowstart, int* __restrict__ cursor){
  __shared__ int pfx;
  int t = threadIdx.x, bid = blockIdx.x;
  if (t < 64){
    int p = 0;
    for (int k = t; k < bid; k += 64) p += blocksum[k];
#pragma unroll
    for (int o=32; o>0; o>>=1) p += __shfl_down(p, o);
    if (t == 0) pfx = p;
  }
  __syncthreads();
  int i = bid*256 + t;
  if (i < NN){
    int rs = tmp[i] - cnt[i] + pfx;
    rowstart[i] = rs; cursor[i] = rs;
  }
}

__global__ __launch_bounds__(256) void scatter_kernel(const int* __restrict__ ei,
                                                      int* __restrict__ cursor, int* __restrict__ csr){
  int e = blockIdx.x*256 + threadIdx.x;
  if (e < NE){
    int r = ei[2*e+1];
    int p = atomicAdd(&cursor[r], 1);
    csr[p] = e;
  }
}

// 2 nodes per wave (half-wave each, float4/lane), 8 gathers in flight, dual accumulators
__global__ __launch_bounds__(256) void segsum_kernel(const int* __restrict__ csr,
                                                     const int* __restrict__ rowstart,
                                                     const int* __restrict__ cnt,
                                                     const float* __restrict__ edge_feats,
                                                     float* __restrict__ acc){
  int tid = threadIdx.x;
  int w = tid>>6, l = tid&63;
  int hh = l>>5, q = l&31;
  int n = blockIdx.x*8 + w*2 + hh;
  if (n >= NN) return;
  int start = rowstart[n], deg = cnt[n];
  floatx4 s0 = floatx4{0.f,0.f,0.f,0.f};
  floatx4 s1 = floatx4{0.f,0.f,0.f,0.f};
  int k = 0;
  for (; k+8 <= deg; k += 8){
    int e0 = csr[start+k],   e1 = csr[start+k+1];
    int e2 = csr[start+k+2], e3 = csr[start+k+3];
    int e4 = csr[start+k+4], e5 = csr[start+k+5];
    int e6 = csr[start+k+6], e7 = csr[start+k+7];
    floatx4 v0 = *(const floatx4*)(edge_feats + (size_t)e0*H + 4*q);
    floatx4 v1 = *(const floatx4*)(edge_feats + (size_t)e1*H + 4*q);
    floatx4 v2 = *(const floatx4*)(edge_feats + (size_t)e2*H + 4*q);
    floatx4 v3 = *(const floatx4*)(edge_feats + (size_t)e3*H + 4*q);
    floatx4 v4 = *(const floatx4*)(edge_feats + (size_t)e4*H + 4*q);
    floatx4 v5 = *(const floatx4*)(edge_feats + (size_t)e5*H + 4*q);
    floatx4 v6 = *(const floatx4*)(edge_feats + (size_t)e6*H + 4*q);
    floatx4 v7 = *(const floatx4*)(edge_feats + (size_t)e7*H + 4*q);
    s0 += v0; s1 += v1; s0 += v2; s1 += v3;
    s0 += v4; s1 += v5; s0 += v6; s1 += v7;
  }
  for (; k+4 <= deg; k += 4){
    int e0 = csr[start+k],   e1 = csr[start+k+1];
    int e2 = csr[start+k+2], e3 = csr[start+k+3];
    floatx4 v0 = *(const floatx4*)(edge_feats + (size_t)e0*H + 4*q);
    floatx4 v1 = *(const floatx4*)(edge_feats + (size_t)e1*H + 4*q);
    floatx4 v2 = *(const floatx4*)(edge_feats + (size_t)e2*H + 4*q);
    floatx4 v3 = *(const floatx4*)(edge_feats + (size_t)e3*H + 4*q);
    s0 += v0; s1 += v1; s0 += v2; s1 += v3;
  }
  for (; k < deg; ++k){
    int e = csr[start+k];
    s0 += *(const floatx4*)(edge_feats + (size_t)e*H + 4*q);
  }
  s0 += s1;
  *(floatx4*)(acc + (size_t)n*H + 4*q) = s0;
}

// ---------- P projections: Ps = nf@W_s + be1 (bias folded), Pr = nf@W_r ----------
__global__ __launch_bounds__(256) void pproj_kernel(
    const float* __restrict__ node_feats,
    const short* __restrict__ wsf, const short* __restrict__ wrf,
    const float* __restrict__ b1f,
    short* __restrict__ Ps, short* __restrict__ Pr)
{
  const int tid = threadIdx.x;
  const int w = tid>>6, l = tid&63, g = l>>4, lo = l&15;
  int row = blockIdx.x*64 + w*16 + lo;
  bool valid = row < NN;
  int rowc = valid ? row : (NN-1);
  const float* sp = node_feats + (size_t)rowc*H;

  short8 ein[4];
#pragma unroll
  for (int ks=0; ks<4; ++ks){
    const int koff = ks*32 + g*8;
    floatx4 f0 = *(const floatx4*)(sp + koff);
    floatx4 f1 = *(const floatx4*)(sp + koff + 4);
    ein[ks][0]=f2bf(f0[0]); ein[ks][1]=f2bf(f0[1]); ein[ks][2]=f2bf(f0[2]); ein[ks][3]=f2bf(f0[3]);
    ein[ks][4]=f2bf(f1[0]); ein[ks][5]=f2bf(f1[1]); ein[ks][6]=f2bf(f1[2]); ein[ks][7]=f2bf(f1[3]);
  }

  floatx4 as[8], ar[8];
#pragma unroll
  for (int mt=0; mt<8; ++mt){ as[mt] = floatx4{0,0,0,0}; ar[mt] = floatx4{0,0,0,0}; }
#pragma unroll
  for (int ks=0; ks<4; ++ks){
#pragma unroll
    for (int mt=0; mt<8; ++mt){
      short8 wv = *(const short8*)(wsf + ((ks*8+mt)*64 + l)*8);
      as[mt] = __builtin_amdgcn_mfma_f32_16x16x32_bf16(wv, ein[ks], as[mt], 0,0,0);
      short8 wv2 = *(const short8*)(wrf + ((ks*8+mt)*64 + l)*8);
      ar[mt] = __builtin_amdgcn_mfma_f32_16x16x32_bf16(wv2, ein[ks], ar[mt], 0,0,0);
    }
  }

  if (valid){
    short* ps = Ps + (size_t)rowc*H + g*32;
    short* pr = Pr + (size_t)rowc*H + g*32;
#pragma unroll
    for (int mt=0; mt<8; ++mt){
      floatx4 bv = *(const floatx4*)(b1f + (mt*64+l)*4);
      short4v vs, vr;
#pragma unroll
      for (int r=0; r<4; ++r){ vs[r] = f2bf(as[mt][r] + bv[r]); vr[r] = f2bf(ar[mt][r]); }
      *(short4v*)(ps + mt*4) = vs;
      *(short4v*)(pr + mt*4) = vr;
    }
  }
}

// ---------- edge kernel: 512 threads, wA(phase1) in 32KB LDS, wB(phase2) from L2,
// in-register hand-off, R=2, 1-deep ef + P-gather pipelines. Halved LDS -> ~3 blocks/CU
// (was 2 at 64KB) -> more resident waves to hide gather latency (R12: occ 22%, 197us).
template<int R>
__global__ __launch_bounds__(512) void edge_kernel(
    const int* __restrict__ edge_idx,
    const float* __restrict__ edge_feats,
    const short* __restrict__ Ps, const short* __restrict__ Pr,
    const short* __restrict__ wef, const short* __restrict__ w2fB,
    const float* __restrict__ b2f,
    const float* __restrict__ gf,  const float* __restrict__ bgf,
    float* __restrict__ out_edge)
{
  extern __shared__ short smem[];
  short* wA = smem;              // wef: 16384 shorts (32KB)
  const int tid = threadIdx.x;
  const int w = tid>>6, l = tid&63, g = l>>4, lo = l&15;

  int rowc[R]; bool valid[R]; int2 se[R];
#pragma unroll
  for (int b=0; b<R; ++b){
    int row = blockIdx.x*(8*16*R) + w*(16*R) + b*16 + lo;
    valid[b] = row < NE;
    rowc[b]  = valid[b] ? row : (NE-1);
    se[b] = *(const int2*)(edge_idx + 2*rowc[b]);
  }

  // stage wA: 4 rounds x 512 threads x 16B
#pragma unroll
  for (int rnd=0; rnd<4; ++rnd){
    int o = (rnd*512 + tid)*8;
    *(short8*)(wA + o) = *(const short8*)(wef + o);
  }

  // prefetch batch-0 P gathers + batch-0 full ef row (10 loads in flight under staging)
  short8 vs[4], vr[4];
  {
    const short* ps = Ps + (size_t)se[0].x*H + g*32;
    const short* pr = Pr + (size_t)se[0].y*H + g*32;
#pragma unroll
    for (int m2=0; m2<4; ++m2){
      vs[m2] = *(const short8*)(ps + m2*8);
      vr[m2] = *(const short8*)(pr + m2*8);
    }
  }
  floatx4 ef[8];
  {
    const float* sp = edge_feats + (size_t)rowc[0]*H;
#pragma unroll
    for (int ks=0; ks<4; ++ks){
      ef[2*ks]   = *(const floatx4*)(sp + ks*32 + g*8);
      ef[2*ks+1] = *(const floatx4*)(sp + ks*32 + g*8 + 4);
    }
  }
  __syncthreads();

#pragma unroll
  for (int b=0; b<R; ++b){
    // convert current ef -> bf16 fragments (frees ef registers)
    short8 ein[4];
#pragma unroll
    for (int ks=0; ks<4; ++ks){
      ein[ks][0]=f2bf(ef[2*ks][0]);   ein[ks][1]=f2bf(ef[2*ks][1]);
      ein[ks][2]=f2bf(ef[2*ks][2]);   ein[ks][3]=f2bf(ef[2*ks][3]);
      ein[ks][4]=f2bf(ef[2*ks+1][0]); ein[ks][5]=f2bf(ef[2*ks+1][1]);
      ein[ks][6]=f2bf(ef[2*ks+1][2]); ein[ks][7]=f2bf(ef[2*ks+1][3]);
    }

    // issue next batch's full-row ef loads (hide under this batch's MFMA)
    if (b+1 < R){
      const float* sp = edge_feats + (size_t)rowc[b+1]*H;
#pragma unroll
      for (int ks=0; ks<4; ++ks){
        ef[2*ks]   = *(const floatx4*)(sp + ks*32 + g*8);
        ef[2*ks+1] = *(const floatx4*)(sp + ks*32 + g*8 + 4);
      }
    }

    // ---- phase 1: ef @ W_e (weights from LDS) ----
    floatx4 acc[8];
#pragma unroll
    for (int mt=0; mt<8; ++mt) acc[mt] = floatx4{0.f,0.f,0.f,0.f};
#pragma unroll
    for (int ks=0; ks<4; ++ks){
#pragma unroll
      for (int mt=0; mt<8; ++mt){
        short8 wv = *(const short8*)(wA + ((ks*8+mt)*64 + l)*8);   // ds_read_b128
        acc[mt] = __builtin_amdgcn_mfma_f32_16x16x32_bf16(wv, ein[ks], acc[mt], 0,0,0);
      }
    }

    // consume gathers: add Ps[snd] (incl. be1) + Pr[rcv]
#pragma unroll
    for (int m2=0; m2<4; ++m2)
#pragma unroll
      for (int r=0; r<4; ++r){
        acc[2*m2][r]   += bf2f(vs[m2][r])   + bf2f(vr[m2][r]);
        acc[2*m2+1][r] += bf2f(vs[m2][4+r]) + bf2f(vr[m2][4+r]);
      }

    // issue next batch's gathers (hidden under this batch's phase2 + LN)
    if (b+1 < R){
      const short* ps = Ps + (size_t)se[b+1].x*H + g*32;
      const short* pr = Pr + (size_t)se[b+1].y*H + g*32;
#pragma unroll
      for (int m2=0; m2<4; ++m2){
        vs[m2] = *(const short8*)(ps + m2*8);
        vr[m2] = *(const short8*)(pr + m2*8);
      }
    }

    // relu + pack straight into phase-2 B-fragments (in-register hand-off)
    short8 hb[4];
#pragma unroll
    for (int s=0; s<4; ++s){
#pragma unroll
      for (int r=0; r<4; ++r){
        float v0 = acc[2*s][r];
        float v1 = acc[2*s+1][r];
        hb[s][r]   = f2bf(v0 > 0.f ? v0 : 0.f);
        hb[s][4+r] = f2bf(v1 > 0.f ? v1 : 0.f);
      }
    }

    // ---- phase 2: y^T = W2^T @ h^T (+b2 via acc init), wB from global (L2-resident
    // 32KB table shared by all waves; coalesced 16B/lane) ----
#pragma unroll
    for (int mt=0; mt<8; ++mt) acc[mt] = *(const floatx4*)(b2f + (mt*64+l)*4);
#pragma unroll
    for (int s=0; s<4; ++s){
#pragma unroll
      for (int mt=0; mt<8; ++mt){
        short8 wv = *(const short8*)(w2fB + ((s*8+mt)*64 + l)*8);
        acc[mt] = __builtin_amdgcn_mfma_f32_16x16x32_bf16(wv, hb[s], acc[mt], 0,0,0);
      }
    }

    // ---- LayerNorm + residual + store ----
    float sum = 0.f, ssq = 0.f;
#pragma unroll
    for (int mt=0; mt<8; ++mt)
#pragma unroll
      for (int r=0; r<4; ++r){ float v = acc[mt][r]; sum += v; ssq += v*v; }
    sum += __shfl_xor(sum, 16); ssq += __shfl_xor(ssq, 16);
    sum += __shfl_xor(sum, 32); ssq += __shfl_xor(ssq, 32);
    const float mean = sum * (1.f/H);
    const float var  = ssq * (1.f/H) - mean*mean;
    const float rs   = rsqrtf(var + 1e-5f);

    const float* resid = edge_feats + (size_t)rowc[b]*H;
    float* outp = out_edge + (size_t)rowc[b]*H;
#pragma unroll
    for (int mt=0; mt<8; ++mt){
      floatx4 gv  = *(const floatx4*)(gf  + (mt*64+l)*4);
      floatx4 bgv = *(const floatx4*)(bgf + (mt*64+l)*4);
      floatx4 efr = *(const floatx4*)(resid + mt*16 + g*4);
      floatx4 o;
#pragma unroll
      for (int r=0; r<4; ++r) o[r] = efr[r] + (acc[mt][r]-mean)*rs*gv[r] + bgv[r];
      if (valid[b]) *(floatx4*)(outp + mt*16 + g*4) = o;
    }
  }
}

// ---------- node kernel (unchanged, validated; uses old-layout blocks 4/5/6) ----------
__global__ __launch_bounds__(256) void node_kernel(
    const float* __restrict__ node_feats,
    const short* __restrict__ w1f, const short* __restrict__ w2f,
    const float* __restrict__ b1f, const float* __restrict__ b2f,
    const float* __restrict__ gf,  const float* __restrict__ bgf,
    float* __restrict__ out_node)
{
  __shared__ short lds_h[4*2048];
  const int tid = threadIdx.x;
  const int w = tid>>6, l = tid&63, g = l>>4, lo = l&15;
  short* ldsw = lds_h + w*2048;

  int row = blockIdx.x*64 + w*16 + lo;
  bool valid = row < NN;
  int rowc = valid ? row : (NN-1);
  const float* sp0 = node_feats + (size_t)rowc*H;
  const float* sp1 = out_node   + (size_t)rowc*H;   // segsum acc

  floatx4 acc1[8];
#pragma unroll
  for (int mt=0; mt<8; ++mt) acc1[mt] = *(const floatx4*)(b1f + (mt*64+l)*4);

#pragma unroll
  for (int ks=0; ks<8; ++ks){
    const float* sp = (ks<4) ? sp0 : sp1;
    const int koff = (ks&3)*32 + g*8;
    floatx4 f0 = *(const floatx4*)(sp + koff);
    floatx4 f1 = *(const floatx4*)(sp + koff + 4);
    short8 ein;
    ein[0]=f2bf(f0[0]); ein[1]=f2bf(f0[1]); ein[2]=f2bf(f0[2]); ein[3]=f2bf(f0[3]);
    ein[4]=f2bf(f1[0]); ein[5]=f2bf(f1[1]); ein[6]=f2bf(f1[2]); ein[7]=f2bf(f1[3]);
#pragma unroll
    for (int mt=0; mt<8; ++mt){
      short8 wv = *(const short8*)(w1f + ((ks*8+mt)*64 + l)*8);
      acc1[mt] = __builtin_amdgcn_mfma_f32_16x16x32_bf16(wv, ein, acc1[mt], 0,0,0);
    }
  }

#pragma unroll
  for (int mt=0; mt<8; ++mt){
    short4v hv;
#pragma unroll
    for (int r=0; r<4; ++r){
      float v = acc1[mt][r];
      hv[r] = f2bf(v > 0.f ? v : 0.f);
    }
    int off = (lo*256 + mt*32 + g*8) ^ ((lo&7)<<4);
    *(short4v*)((char*)ldsw + off) = hv;
  }

  floatx4 acc2[8];
#pragma unroll
  for (int mt=0; mt<8; ++mt) acc2[mt] = *(const floatx4*)(b2f + (mt*64+l)*4);

#pragma unroll
  for (int s=0; s<4; ++s){
    int roff = (lo*256 + s*64 + g*16) ^ ((lo&7)<<4);
    short8 hb = *(const short8*)((char*)ldsw + roff);
#pragma unroll
    for (int mt=0; mt<8; ++mt){
      short8 wv = *(const short8*)(w2f + ((s*8+mt)*64 + l)*8);
      acc2[mt] = __builtin_amdgcn_mfma_f32_16x16x32_bf16(wv, hb, acc2[mt], 0,0,0);
    }
  }

  float sum = 0.f, ssq = 0.f;
#pragma unroll
  for (int mt=0; mt<8; ++mt)
#pragma unroll
    for (int r=0; r<4; ++r){ float v = acc2[mt][r]; sum += v; ssq += v*v; }
  sum += __shfl_xor(sum, 16); ssq += __shfl_xor(ssq, 16);
  sum += __shfl_xor(sum, 32); ssq += __shfl_xor(ssq, 32);
  const float mean = sum * (1.f/H);
  const float var  = ssq * (1.f/H) - mean*mean;
  const float rs   = rsqrtf(var + 1e-5f);

#pragma unroll
  for (int mt=0; mt<8; ++mt){
    floatx4 gv  = *(const floatx4*)(gf  + (mt*64+l)*4);
    floatx4 bgv = *(const floatx4*)(bgf + (mt*64+l)*4);
    floatx4 nf  = *(const floatx4*)(node_feats + (size_t)rowc*H + mt*16 + g*4);
    floatx4 o;
#pragma unroll
    for (int r=0; r<4; ++r) o[r] = nf[r] + (acc2[mt][r]-mean)*rs*gv[r] + bgv[r];
    if (valid) *(floatx4*)(out_node + (size_t)rowc*H + mt*16 + g*4) = o;
  }
}

extern "C" void kernel_launch(void* const* d_in, const int* in_sizes, int n_in,
                              void* d_out, int out_size, void* d_ws, size_t ws_size,
                              hipStream_t stream)
{
  const int*   edge_idx   = (const int*)  d_in[0];
  const float* node_feats = (const float*)d_in[1];
  const float* edge_feats = (const float*)d_in[2];
  const float* We1=(const float*)d_in[3];  const float* be1=(const float*)d_in[4];
  const float* We2=(const float*)d_in[5];  const float* be2=(const float*)d_in[6];
  const float* ge =(const float*)d_in[7];  const float* bge=(const float*)d_in[8];
  const float* Wn1=(const float*)d_in[9];  const float* bn1=(const float*)d_in[10];
  const float* Wn2=(const float*)d_in[11]; const float* bn2=(const float*)d_in[12];
  const float* gn =(const float*)d_in[13]; const float* bgn=(const float*)d_in[14];

  float* out_node = (float*)d_out;                    // doubles as segsum acc
  float* out_edge = out_node + (size_t)NN*H;

  char* ws = (char*)d_ws;
  short* wf      = (short*)ws;
  float* bf      = (float*)(ws + OFF_BF);
  short* Ps      = (short*)(ws + OFF_PS);
  short* Pr      = (short*)(ws + OFF_PR);
  int* cnt       = (int*)(ws + OFF_CNT);
  int* tmp       = (int*)(ws + OFF_TMP);
  int* rowstart  = (int*)(ws + OFF_RS);
  int* cursor    = (int*)(ws + OFF_CUR);
  int* blocksum  = (int*)(ws + OFF_BSUM);
  int* csr       = (int*)(ws + OFF_CSR);

  short* wsf  = wf;                 // We1 rows 0-127
  short* wrf  = wf + 16384;         // We1 rows 128-255
  short* wef  = wf + 32768;         // We1 rows 256-383
  short* wn1f = wf + 65536;         // Wn1 (8 ks, blocks 4+5)
  short* wn2f = wf + 98304;         // Wn2 (block 6)
  short* w2fB = wf + 114688;        // We2, phase2-B layout (block 7)
  float* b1f  = bf;         float* b2f  = bf + 2048;
  float* gef  = bf + 4096;  float* bgef = bf + 6144;
  float* bn1f = bf + 8192;  float* bn2f = bf + 10240;
  float* gnf  = bf + 12288; float* bgnf = bf + 14336;

  // prep (weights+biases) + cnt zeroing, one launch
  prep_kernel<<<(PREP_TOTAL + 255)/256, 256, 0, stream>>>(
      We1, We2, Wn1, Wn2, be1, be2, ge, bge, bn1, bn2, gn, bgn, wf, bf, cnt);

  // CSR build (scan2 folded into scan3)
  hist_kernel<<<(NE+255)/256, 256, 0, stream>>>(edge_idx, cnt);
  scan1_kernel<<<NB1, 256, 0, stream>>>(cnt, tmp, blocksum);
  scan3_kernel<<<NB1, 256, 0, stream>>>(cnt, tmp, blocksum, rowstart, cursor);
  scatter_kernel<<<(NE+255)/256, 256, 0, stream>>>(edge_idx, cursor, csr);

  // node projections for edge phase-1 (Ps = nf@W_s + be1, Pr = nf@W_r)
  pproj_kernel<<<(NN+63)/64, 256, 0, stream>>>(node_feats, wsf, wrf, b1f, Ps, Pr);

  // edge MLP: 512-thread blocks, 32KB LDS (wA only; wB from L2), R=2
  edge_kernel<2><<<(NE + 255)/256, 512, 32768, stream>>>(
      edge_idx, edge_feats, Ps, Pr, wef, w2fB, b2f, gef, bgef, out_edge);

  // segment_sum into out_node (acc), then node MLP consumes + overwrites
  segsum_kernel<<<(NN+7)/8, 256, 0, stream>>>(csr, rowstart, cnt, edge_feats, out_node);

  node_kernel<<<(NN+63)/64, 256, 0, stream>>>(
      node_feats, wn1f, wn2f, bn1f, bn2f, gnf, bgnf, out_node);
}

// Round 14
// 371.697 us; speedup vs baseline: 1.0218x; 1.0218x over previous
//
#include <hip/hip_runtime.h>
#include <hip/hip_bf16.h>

#define DI __device__ __forceinline__

typedef __attribute__((ext_vector_type(8))) short short8;   // 8 bf16 (4 VGPR)
typedef __attribute__((ext_vector_type(4))) short short4v;  // 4 bf16 (8B)
typedef __attribute__((ext_vector_type(4))) float floatx4;

constexpr int NN = 50000;
constexpr int NE = 500000;
constexpr int H  = 128;
constexpr int NB1 = (NN + 255) / 256;   // scan blocks

// ---- ws layout (bytes) ----
constexpr size_t OFF_BF   = 262144;
constexpr size_t OFF_PS   = 327680;
constexpr size_t OFF_PR   = 13127680;
constexpr size_t OFF_CNT  = 25927680;
constexpr size_t OFF_TMP  = 26127680;
constexpr size_t OFF_RS   = 26327680;
constexpr size_t OFF_CUR  = 26527680;
constexpr size_t OFF_BSUM = 26727680;
constexpr size_t OFF_CSR  = 26728704;

constexpr int WF_TOTAL = 131072;      // 8*16384 shorts
constexpr int BIASF_FLOATS = 8*2048;
constexpr int PREP_TOTAL = WF_TOTAL + BIASF_FLOATS + NN;   // + zero_cnt fold

// fused-grid geometry: groups of 5 blocks = 2 edge-role + 3 seg-role
constexpr int EB = (NE + 255) / 256;   // 1954 edge tiles (512 thr, R=2 -> 256 edges)
constexpr int SB = (NN + 15) / 16;     // 3125 seg tiles (512 thr, 16 nodes)
constexpr int FUSE_GROUPS = (SB + 2) / 3 > (EB + 1) / 2 ? (SB + 2) / 3 : (EB + 1) / 2; // 1042
constexpr int FUSE_GRID = FUSE_GROUPS * 5;   // 5210

DI short f2bf(float f){ __bf16 b = (__bf16)f; return __builtin_bit_cast(short, b); }
DI float bf2f(short s){ return __builtin_bit_cast(float, ((unsigned)(unsigned short)s) << 16); }

// Weight frags. Standard blocks: t=((ks*8+nt)*64+l)*8+j <-> W[roff+32ks+8(l>>4)+j][16nt+(l&15)]
// Block 7 (phase2-B map): row = 32ks + 16*(j>>2) + 4*(l>>4) + (j&3). Tail range zeroes cnt.
__global__ __launch_bounds__(256) void prep_kernel(
    const float* __restrict__ We1, const float* __restrict__ We2,
    const float* __restrict__ Wn1, const float* __restrict__ Wn2,
    const float* __restrict__ be1, const float* __restrict__ be2,
    const float* __restrict__ ge,  const float* __restrict__ bge,
    const float* __restrict__ bn1, const float* __restrict__ bn2,
    const float* __restrict__ gn,  const float* __restrict__ bgn,
    short* __restrict__ wf, float* __restrict__ bf, int* __restrict__ cnt)
{
  int t = blockIdx.x*256 + threadIdx.x;
  if (t < WF_TOTAL) {
    int blk = t >> 14, u = t & 16383;
    int j = u & 7, l = (u>>3)&63, nt = (u>>9)&7, ks = u>>12;
    const float* src; int roff; bool blayout = false;
    switch (blk) {
      case 0: src = We1; roff = 0;   break;
      case 1: src = We1; roff = 128; break;
      case 2: src = We1; roff = 256; break;
      case 3: src = We2; roff = 0;   break;
      case 4: src = Wn1; roff = 0;   break;
      case 5: src = Wn1; roff = 128; break;
      case 6: src = Wn2; roff = 0;   break;
      default: src = We2; roff = 0; blayout = true; break;
    }
    int row = blayout ? (32*ks + 16*(j>>2) + 4*(l>>4) + (j&3))
                      : (roff + 32*ks + 8*(l>>4) + j);
    int col = 16*nt + (l&15);
    wf[t] = f2bf(src[row*H + col]);
  } else if (t < WF_TOTAL + BIASF_FLOATS) {
    int tb = t - WF_TOTAL;
    int arr = tb >> 11, u = tb & 2047;
    int r = u&3, l = (u>>2)&63, mt = u>>8;
    int feat = 16*mt + 4*(l>>4) + r;
    const float* s;
    switch (arr) {
      case 0: s = be1; break; case 1: s = be2; break;
      case 2: s = ge;  break; case 3: s = bge; break;
      case 4: s = bn1; break; case 5: s = bn2; break;
      case 6: s = gn;  break; default: s = bgn; break;
    }
    bf[tb] = s[feat];
  } else if (t < PREP_TOTAL) {
    cnt[t - WF_TOTAL - BIASF_FLOATS] = 0;
  }
}

// ---------- CSR build ----------
__global__ __launch_bounds__(256) void hist_kernel(const int* __restrict__ ei, int* __restrict__ cnt){
  int e = blockIdx.x*256 + threadIdx.x;
  if (e < NE) atomicAdd(&cnt[ei[2*e+1]], 1);
}

__global__ __launch_bounds__(256) void scan1_kernel(const int* __restrict__ cnt,
                                                    int* __restrict__ tmp, int* __restrict__ blocksum){
  __shared__ int s[256];
  int t = threadIdx.x, i = blockIdx.x*256 + t;
  int v = (i < NN) ? cnt[i] : 0;
  s[t] = v; __syncthreads();
#pragma unroll
  for (int o=1; o<256; o<<=1){
    int u = (t >= o) ? s[t-o] : 0;
    __syncthreads();
    s[t] += u;
    __syncthreads();
  }
  if (i < NN) tmp[i] = s[t];
  if (t == 255) blocksum[blockIdx.x] = s[255];
}

// scan2 folded in: every block computes its own exclusive prefix over blocksum[0..bid)
__global__ __launch_bounds__(256) void scan3_kernel(const int* __restrict__ cnt, const int* __restrict__ tmp,
                                                    const int* __restrict__ blocksum,
                                                    int* __restrict__ rowstart, int* __restrict__ cursor){
  __shared__ int pfx;
  int t = threadIdx.x, bid = blockIdx.x;
  if (t < 64){
    int p = 0;
    for (int k = t; k < bid; k += 64) p += blocksum[k];
#pragma unroll
    for (int o=32; o>0; o>>=1) p += __shfl_down(p, o);
    if (t == 0) pfx = p;
  }
  __syncthreads();
  int i = bid*256 + t;
  if (i < NN){
    int rs = tmp[i] - cnt[i] + pfx;
    rowstart[i] = rs; cursor[i] = rs;
  }
}

__global__ __launch_bounds__(256) void scatter_kernel(const int* __restrict__ ei,
                                                      int* __restrict__ cursor, int* __restrict__ csr){
  int e = blockIdx.x*256 + threadIdx.x;
  if (e < NE){
    int r = ei[2*e+1];
    int p = atomicAdd(&cursor[r], 1);
    csr[p] = e;
  }
}

// ---------- P projections: Ps = nf@W_s + be1 (bias folded), Pr = nf@W_r ----------
__global__ __launch_bounds__(256) void pproj_kernel(
    const float* __restrict__ node_feats,
    const short* __restrict__ wsf, const short* __restrict__ wrf,
    const float* __restrict__ b1f,
    short* __restrict__ Ps, short* __restrict__ Pr)
{
  const int tid = threadIdx.x;
  const int w = tid>>6, l = tid&63, g = l>>4, lo = l&15;
  int row = blockIdx.x*64 + w*16 + lo;
  bool valid = row < NN;
  int rowc = valid ? row : (NN-1);
  const float* sp = node_feats + (size_t)rowc*H;

  short8 ein[4];
#pragma unroll
  for (int ks=0; ks<4; ++ks){
    const int koff = ks*32 + g*8;
    floatx4 f0 = *(const floatx4*)(sp + koff);
    floatx4 f1 = *(const floatx4*)(sp + koff + 4);
    ein[ks][0]=f2bf(f0[0]); ein[ks][1]=f2bf(f0[1]); ein[ks][2]=f2bf(f0[2]); ein[ks][3]=f2bf(f0[3]);
    ein[ks][4]=f2bf(f1[0]); ein[ks][5]=f2bf(f1[1]); ein[ks][6]=f2bf(f1[2]); ein[ks][7]=f2bf(f1[3]);
  }

  floatx4 as[8], ar[8];
#pragma unroll
  for (int mt=0; mt<8; ++mt){ as[mt] = floatx4{0,0,0,0}; ar[mt] = floatx4{0,0,0,0}; }
#pragma unroll
  for (int ks=0; ks<4; ++ks){
#pragma unroll
    for (int mt=0; mt<8; ++mt){
      short8 wv = *(const short8*)(wsf + ((ks*8+mt)*64 + l)*8);
      as[mt] = __builtin_amdgcn_mfma_f32_16x16x32_bf16(wv, ein[ks], as[mt], 0,0,0);
      short8 wv2 = *(const short8*)(wrf + ((ks*8+mt)*64 + l)*8);
      ar[mt] = __builtin_amdgcn_mfma_f32_16x16x32_bf16(wv2, ein[ks], ar[mt], 0,0,0);
    }
  }

  if (valid){
    short* ps = Ps + (size_t)rowc*H + g*32;
    short* pr = Pr + (size_t)rowc*H + g*32;
#pragma unroll
    for (int mt=0; mt<8; ++mt){
      floatx4 bv = *(const floatx4*)(b1f + (mt*64+l)*4);
      short4v vs, vr;
#pragma unroll
      for (int r=0; r<4; ++r){ vs[r] = f2bf(as[mt][r] + bv[r]); vr[r] = f2bf(ar[mt][r]); }
      *(short4v*)(ps + mt*4) = vs;
      *(short4v*)(pr + mt*4) = vr;
    }
  }
}

// ---------- fused kernel: edge-MLP blocks + segsum blocks, 512 threads ----------
// Groups of 5 blocks: bid%5 in {0,1} -> edge role (R12-exact body, VGPR~72),
// {2,3,4} -> segsum role (16 nodes/block). Seg role runs in edge's latency
// bubbles; R9's fusion failure causes (1024-thr VGPR=64 pin + R=4 spill) absent here.
template<int R>
__global__ __launch_bounds__(512) void fused_kernel(
    const int* __restrict__ edge_idx,
    const float* __restrict__ edge_feats,
    const short* __restrict__ Ps, const short* __restrict__ Pr,
    const short* __restrict__ wef, const short* __restrict__ w2fB,
    const float* __restrict__ b2f,
    const float* __restrict__ gf,  const float* __restrict__ bgf,
    float* __restrict__ out_edge,
    const int* __restrict__ csr, const int* __restrict__ rowstart,
    const int* __restrict__ cnt, float* __restrict__ acc_out)
{
  extern __shared__ short smem[];
  const int bid = blockIdx.x;
  const int tid = threadIdx.x;
  const int m5 = bid % 5, gq = bid / 5;

  if (m5 >= 2) {
    // ---------------- segsum role: 16 nodes per 512-thread block ----------------
    int sb = gq*3 + (m5 - 2);
    if (sb >= SB) return;
    int w = tid>>6, l = tid&63;
    int hh = l>>5, q = l&31;
    int n = sb*16 + w*2 + hh;
    if (n >= NN) return;
    int start = rowstart[n], deg = cnt[n];
    floatx4 s0 = floatx4{0.f,0.f,0.f,0.f};
    floatx4 s1 = floatx4{0.f,0.f,0.f,0.f};
    int k = 0;
    for (; k+8 <= deg; k += 8){
      int e0 = csr[start+k],   e1 = csr[start+k+1];
      int e2 = csr[start+k+2], e3 = csr[start+k+3];
      int e4 = csr[start+k+4], e5 = csr[start+k+5];
      int e6 = csr[start+k+6], e7 = csr[start+k+7];
      floatx4 v0 = *(const floatx4*)(edge_feats + (size_t)e0*H + 4*q);
      floatx4 v1 = *(const floatx4*)(edge_feats + (size_t)e1*H + 4*q);
      floatx4 v2 = *(const floatx4*)(edge_feats + (size_t)e2*H + 4*q);
      floatx4 v3 = *(const floatx4*)(edge_feats + (size_t)e3*H + 4*q);
      floatx4 v4 = *(const floatx4*)(edge_feats + (size_t)e4*H + 4*q);
      floatx4 v5 = *(const floatx4*)(edge_feats + (size_t)e5*H + 4*q);
      floatx4 v6 = *(const floatx4*)(edge_feats + (size_t)e6*H + 4*q);
      floatx4 v7 = *(const floatx4*)(edge_feats + (size_t)e7*H + 4*q);
      s0 += v0; s1 += v1; s0 += v2; s1 += v3;
      s0 += v4; s1 += v5; s0 += v6; s1 += v7;
    }
    for (; k+4 <= deg; k += 4){
      int e0 = csr[start+k],   e1 = csr[start+k+1];
      int e2 = csr[start+k+2], e3 = csr[start+k+3];
      floatx4 v0 = *(const floatx4*)(edge_feats + (size_t)e0*H + 4*q);
      floatx4 v1 = *(const floatx4*)(edge_feats + (size_t)e1*H + 4*q);
      floatx4 v2 = *(const floatx4*)(edge_feats + (size_t)e2*H + 4*q);
      floatx4 v3 = *(const floatx4*)(edge_feats + (size_t)e3*H + 4*q);
      s0 += v0; s1 += v1; s0 += v2; s1 += v3;
    }
    for (; k < deg; ++k){
      int e = csr[start+k];
      s0 += *(const floatx4*)(edge_feats + (size_t)e*H + 4*q);
    }
    s0 += s1;
    *(floatx4*)(acc_out + (size_t)n*H + 4*q) = s0;
    return;
  }

  // ---------------- edge role (R12-exact body) ----------------
  int eb = gq*2 + m5;
  if (eb >= EB) return;
  short* wA = smem;              // wef:  16384 shorts (32KB)
  short* wB = smem + 16384;      // w2fB: 16384 shorts (32KB)
  const int w = tid>>6, l = tid&63, g = l>>4, lo = l&15;

  int rowc[R]; bool valid[R]; int2 se[R];
#pragma unroll
  for (int b=0; b<R; ++b){
    int row = eb*(8*16*R) + w*(16*R) + b*16 + lo;
    valid[b] = row < NE;
    rowc[b]  = valid[b] ? row : (NE-1);
    se[b] = *(const int2*)(edge_idx + 2*rowc[b]);
  }

  // stage weights: 4 rounds x 512 threads x 16B per matrix
#pragma unroll
  for (int rnd=0; rnd<4; ++rnd){
    int o = (rnd*512 + tid)*8;
    *(short8*)(wA + o) = *(const short8*)(wef  + o);
    *(short8*)(wB + o) = *(const short8*)(w2fB + o);
  }

  // prefetch batch-0 P gathers + batch-0 full ef row (10 loads in flight under staging)
  short8 vs[4], vr[4];
  {
    const short* ps = Ps + (size_t)se[0].x*H + g*32;
    const short* pr = Pr + (size_t)se[0].y*H + g*32;
#pragma unroll
    for (int m2=0; m2<4; ++m2){
      vs[m2] = *(const short8*)(ps + m2*8);
      vr[m2] = *(const short8*)(pr + m2*8);
    }
  }
  floatx4 ef[8];
  {
    const float* sp = edge_feats + (size_t)rowc[0]*H;
#pragma unroll
    for (int ks=0; ks<4; ++ks){
      ef[2*ks]   = *(const floatx4*)(sp + ks*32 + g*8);
      ef[2*ks+1] = *(const floatx4*)(sp + ks*32 + g*8 + 4);
    }
  }
  __syncthreads();

#pragma unroll
  for (int b=0; b<R; ++b){
    // convert current ef -> bf16 fragments (frees ef registers)
    short8 ein[4];
#pragma unroll
    for (int ks=0; ks<4; ++ks){
      ein[ks][0]=f2bf(ef[2*ks][0]);   ein[ks][1]=f2bf(ef[2*ks][1]);
      ein[ks][2]=f2bf(ef[2*ks][2]);   ein[ks][3]=f2bf(ef[2*ks][3]);
      ein[ks][4]=f2bf(ef[2*ks+1][0]); ein[ks][5]=f2bf(ef[2*ks+1][1]);
      ein[ks][6]=f2bf(ef[2*ks+1][2]); ein[ks][7]=f2bf(ef[2*ks+1][3]);
    }

    // issue next batch's full-row ef loads (hide under this batch's MFMA)
    if (b+1 < R){
      const float* sp = edge_feats + (size_t)rowc[b+1]*H;
#pragma unroll
      for (int ks=0; ks<4; ++ks){
        ef[2*ks]   = *(const floatx4*)(sp + ks*32 + g*8);
        ef[2*ks+1] = *(const floatx4*)(sp + ks*32 + g*8 + 4);
      }
    }

    // ---- phase 1: ef @ W_e (weights from LDS) ----
    floatx4 acc[8];
#pragma unroll
    for (int mt=0; mt<8; ++mt) acc[mt] = floatx4{0.f,0.f,0.f,0.f};
#pragma unroll
    for (int ks=0; ks<4; ++ks){
#pragma unroll
      for (int mt=0; mt<8; ++mt){
        short8 wv = *(const short8*)(wA + ((ks*8+mt)*64 + l)*8);   // ds_read_b128
        acc[mt] = __builtin_amdgcn_mfma_f32_16x16x32_bf16(wv, ein[ks], acc[mt], 0,0,0);
      }
    }

    // consume gathers: add Ps[snd] (incl. be1) + Pr[rcv]
#pragma unroll
    for (int m2=0; m2<4; ++m2)
#pragma unroll
      for (int r=0; r<4; ++r){
        acc[2*m2][r]   += bf2f(vs[m2][r])   + bf2f(vr[m2][r]);
        acc[2*m2+1][r] += bf2f(vs[m2][4+r]) + bf2f(vr[m2][4+r]);
      }

    // issue next batch's gathers (hidden under this batch's phase2 + LN)
    if (b+1 < R){
      const short* ps = Ps + (size_t)se[b+1].x*H + g*32;
      const short* pr = Pr + (size_t)se[b+1].y*H + g*32;
#pragma unroll
      for (int m2=0; m2<4; ++m2){
        vs[m2] = *(const short8*)(ps + m2*8);
        vr[m2] = *(const short8*)(pr + m2*8);
      }
    }

    // relu + pack straight into phase-2 B-fragments (in-register hand-off)
    short8 hb[4];
#pragma unroll
    for (int s=0; s<4; ++s){
#pragma unroll
      for (int r=0; r<4; ++r){
        float v0 = acc[2*s][r];
        float v1 = acc[2*s+1][r];
        hb[s][r]   = f2bf(v0 > 0.f ? v0 : 0.f);
        hb[s][4+r] = f2bf(v1 > 0.f ? v1 : 0.f);
      }
    }

    // ---- phase 2: y^T = W2^T @ h^T (+b2 via acc init) ----
#pragma unroll
    for (int mt=0; mt<8; ++mt) acc[mt] = *(const floatx4*)(b2f + (mt*64+l)*4);
#pragma unroll
    for (int s=0; s<4; ++s){
#pragma unroll
      for (int mt=0; mt<8; ++mt){
        short8 wv = *(const short8*)(wB + ((s*8+mt)*64 + l)*8);   // ds_read_b128
        acc[mt] = __builtin_amdgcn_mfma_f32_16x16x32_bf16(wv, hb[s], acc[mt], 0,0,0);
      }
    }

    // ---- LayerNorm + residual + store ----
    float sum = 0.f, ssq = 0.f;
#pragma unroll
    for (int mt=0; mt<8; ++mt)
#pragma unroll
      for (int r=0; r<4; ++r){ float v = acc[mt][r]; sum += v; ssq += v*v; }
    sum += __shfl_xor(sum, 16); ssq += __shfl_xor(ssq, 16);
    sum += __shfl_xor(sum, 32); ssq += __shfl_xor(ssq, 32);
    const float mean = sum * (1.f/H);
    const float var  = ssq * (1.f/H) - mean*mean;
    const float rs   = rsqrtf(var + 1e-5f);

    const float* resid = edge_feats + (size_t)rowc[b]*H;
    float* outp = out_edge + (size_t)rowc[b]*H;
#pragma unroll
    for (int mt=0; mt<8; ++mt){
      floatx4 gv  = *(const floatx4*)(gf  + (mt*64+l)*4);
      floatx4 bgv = *(const floatx4*)(bgf + (mt*64+l)*4);
      floatx4 efr = *(const floatx4*)(resid + mt*16 + g*4);
      floatx4 o;
#pragma unroll
      for (int r=0; r<4; ++r) o[r] = efr[r] + (acc[mt][r]-mean)*rs*gv[r] + bgv[r];
      if (valid[b]) *(floatx4*)(outp + mt*16 + g*4) = o;
    }
  }
}

// ---------- node kernel (unchanged, validated; uses old-layout blocks 4/5/6) ----------
__global__ __launch_bounds__(256) void node_kernel(
    const float* __restrict__ node_feats,
    const short* __restrict__ w1f, const short* __restrict__ w2f,
    const float* __restrict__ b1f, const float* __restrict__ b2f,
    const float* __restrict__ gf,  const float* __restrict__ bgf,
    float* __restrict__ out_node)
{
  __shared__ short lds_h[4*2048];
  const int tid = threadIdx.x;
  const int w = tid>>6, l = tid&63, g = l>>4, lo = l&15;
  short* ldsw = lds_h + w*2048;

  int row = blockIdx.x*64 + w*16 + lo;
  bool valid = row < NN;
  int rowc = valid ? row : (NN-1);
  const float* sp0 = node_feats + (size_t)rowc*H;
  const float* sp1 = out_node   + (size_t)rowc*H;   // segsum acc

  floatx4 acc1[8];
#pragma unroll
  for (int mt=0; mt<8; ++mt) acc1[mt] = *(const floatx4*)(b1f + (mt*64+l)*4);

#pragma unroll
  for (int ks=0; ks<8; ++ks){
    const float* sp = (ks<4) ? sp0 : sp1;
    const int koff = (ks&3)*32 + g*8;
    floatx4 f0 = *(const floatx4*)(sp + koff);
    floatx4 f1 = *(const floatx4*)(sp + koff + 4);
    short8 ein;
    ein[0]=f2bf(f0[0]); ein[1]=f2bf(f0[1]); ein[2]=f2bf(f0[2]); ein[3]=f2bf(f0[3]);
    ein[4]=f2bf(f1[0]); ein[5]=f2bf(f1[1]); ein[6]=f2bf(f1[2]); ein[7]=f2bf(f1[3]);
#pragma unroll
    for (int mt=0; mt<8; ++mt){
      short8 wv = *(const short8*)(w1f + ((ks*8+mt)*64 + l)*8);
      acc1[mt] = __builtin_amdgcn_mfma_f32_16x16x32_bf16(wv, ein, acc1[mt], 0,0,0);
    }
  }

#pragma unroll
  for (int mt=0; mt<8; ++mt){
    short4v hv;
#pragma unroll
    for (int r=0; r<4; ++r){
      float v = acc1[mt][r];
      hv[r] = f2bf(v > 0.f ? v : 0.f);
    }
    int off = (lo*256 + mt*32 + g*8) ^ ((lo&7)<<4);
    *(short4v*)((char*)ldsw + off) = hv;
  }

  floatx4 acc2[8];
#pragma unroll
  for (int mt=0; mt<8; ++mt) acc2[mt] = *(const floatx4*)(b2f + (mt*64+l)*4);

#pragma unroll
  for (int s=0; s<4; ++s){
    int roff = (lo*256 + s*64 + g*16) ^ ((lo&7)<<4);
    short8 hb = *(const short8*)((char*)ldsw + roff);
#pragma unroll
    for (int mt=0; mt<8; ++mt){
      short8 wv = *(const short8*)(w2f + ((s*8+mt)*64 + l)*8);
      acc2[mt] = __builtin_amdgcn_mfma_f32_16x16x32_bf16(wv, hb, acc2[mt], 0,0,0);
    }
  }

  float sum = 0.f, ssq = 0.f;
#pragma unroll
  for (int mt=0; mt<8; ++mt)
#pragma unroll
    for (int r=0; r<4; ++r){ float v = acc2[mt][r]; sum += v; ssq += v*v; }
  sum += __shfl_xor(sum, 16); ssq += __shfl_xor(ssq, 16);
  sum += __shfl_xor(sum, 32); ssq += __shfl_xor(ssq, 32);
  const float mean = sum * (1.f/H);
  const float var  = ssq * (1.f/H) - mean*mean;
  const float rs   = rsqrtf(var + 1e-5f);

#pragma unroll
  for (int mt=0; mt<8; ++mt){
    floatx4 gv  = *(const floatx4*)(gf  + (mt*64+l)*4);
    floatx4 bgv = *(const floatx4*)(bgf + (mt*64+l)*4);
    floatx4 nf  = *(const floatx4*)(node_feats + (size_t)rowc*H + mt*16 + g*4);
    floatx4 o;
#pragma unroll
    for (int r=0; r<4; ++r) o[r] = nf[r] + (acc2[mt][r]-mean)*rs*gv[r] + bgv[r];
    if (valid) *(floatx4*)(out_node + (size_t)rowc*H + mt*16 + g*4) = o;
  }
}

extern "C" void kernel_launch(void* const* d_in, const int* in_sizes, int n_in,
                              void* d_out, int out_size, void* d_ws, size_t ws_size,
                              hipStream_t stream)
{
  const int*   edge_idx   = (const int*)  d_in[0];
  const float* node_feats = (const float*)d_in[1];
  const float* edge_feats = (const float*)d_in[2];
  const float* We1=(const float*)d_in[3];  const float* be1=(const float*)d_in[4];
  const float* We2=(const float*)d_in[5];  const float* be2=(const float*)d_in[6];
  const float* ge =(const float*)d_in[7];  const float* bge=(const float*)d_in[8];
  const float* Wn1=(const float*)d_in[9];  const float* bn1=(const float*)d_in[10];
  const float* Wn2=(const float*)d_in[11]; const float* bn2=(const float*)d_in[12];
  const float* gn =(const float*)d_in[13]; const float* bgn=(const float*)d_in[14];

  float* out_node = (float*)d_out;                    // doubles as segsum acc
  float* out_edge = out_node + (size_t)NN*H;

  char* ws = (char*)d_ws;
  short* wf      = (short*)ws;
  float* bf      = (float*)(ws + OFF_BF);
  short* Ps      = (short*)(ws + OFF_PS);
  short* Pr      = (short*)(ws + OFF_PR);
  int* cnt       = (int*)(ws + OFF_CNT);
  int* tmp       = (int*)(ws + OFF_TMP);
  int* rowstart  = (int*)(ws + OFF_RS);
  int* cursor    = (int*)(ws + OFF_CUR);
  int* blocksum  = (int*)(ws + OFF_BSUM);
  int* csr       = (int*)(ws + OFF_CSR);

  short* wsf  = wf;                 // We1 rows 0-127
  short* wrf  = wf + 16384;         // We1 rows 128-255
  short* wef  = wf + 32768;         // We1 rows 256-383
  short* wn1f = wf + 65536;         // Wn1 (8 ks, blocks 4+5)
  short* wn2f = wf + 98304;         // Wn2 (block 6)
  short* w2fB = wf + 114688;        // We2, phase2-B layout (block 7)
  float* b1f  = bf;         float* b2f  = bf + 2048;
  float* gef  = bf + 4096;  float* bgef = bf + 6144;
  float* bn1f = bf + 8192;  float* bn2f = bf + 10240;
  float* gnf  = bf + 12288; float* bgnf = bf + 14336;

  // prep (weights+biases) + cnt zeroing, one launch
  prep_kernel<<<(PREP_TOTAL + 255)/256, 256, 0, stream>>>(
      We1, We2, Wn1, Wn2, be1, be2, ge, bge, bn1, bn2, gn, bgn, wf, bf, cnt);

  // CSR build (scan2 folded into scan3)
  hist_kernel<<<(NE+255)/256, 256, 0, stream>>>(edge_idx, cnt);
  scan1_kernel<<<NB1, 256, 0, stream>>>(cnt, tmp, blocksum);
  scan3_kernel<<<NB1, 256, 0, stream>>>(cnt, tmp, blocksum, rowstart, cursor);
  scatter_kernel<<<(NE+255)/256, 256, 0, stream>>>(edge_idx, cursor, csr);

  // node projections for edge phase-1 (Ps = nf@W_s + be1, Pr = nf@W_r)
  pproj_kernel<<<(NN+63)/64, 256, 0, stream>>>(node_feats, wsf, wrf, b1f, Ps, Pr);

  // fused edge-MLP + segsum: 512-thread blocks, 64KB LDS (edge role), 2:3 interleave
  fused_kernel<2><<<FUSE_GRID, 512, 65536, stream>>>(
      edge_idx, edge_feats, Ps, Pr, wef, w2fB, b2f, gef, bgef, out_edge,
      csr, rowstart, cnt, out_node);

  node_kernel<<<(NN+63)/64, 256, 0, stream>>>(
      node_feats, wn1f, wn2f, bn1f, bn2f, gnf, bgnf, out_node);
}

// Round 15
// 351.330 us; speedup vs baseline: 1.0810x; 1.0580x over previous
//
#include <hip/hip_runtime.h>
#include <hip/hip_bf16.h>

#define DI __device__ __forceinline__

typedef __attribute__((ext_vector_type(8))) short short8;   // 8 bf16 (4 VGPR)
typedef __attribute__((ext_vector_type(4))) short short4v;  // 4 bf16 (8B)
typedef __attribute__((ext_vector_type(4))) float floatx4;

constexpr int NN = 50000;
constexpr int NE = 500000;
constexpr int H  = 128;
constexpr int NB1 = (NN + 255) / 256;   // scan blocks

// ---- ws layout (bytes) ----
constexpr size_t OFF_BF   = 262144;
constexpr size_t OFF_PS   = 327680;
constexpr size_t OFF_PR   = 13127680;
constexpr size_t OFF_CNT  = 25927680;
constexpr size_t OFF_TMP  = 26127680;
constexpr size_t OFF_RS   = 26327680;
constexpr size_t OFF_CUR  = 26527680;
constexpr size_t OFF_BSUM = 26727680;
constexpr size_t OFF_CSR  = 26728704;

constexpr int WF_TOTAL = 131072;      // 8*16384 shorts
constexpr int BIASF_FLOATS = 8*2048;
constexpr int PREP_TOTAL = WF_TOTAL + BIASF_FLOATS + NN;   // + zero_cnt fold

DI short f2bf(float f){ __bf16 b = (__bf16)f; return __builtin_bit_cast(short, b); }
DI float bf2f(short s){ return __builtin_bit_cast(float, ((unsigned)(unsigned short)s) << 16); }

// Weight frags. Standard blocks: t=((ks*8+nt)*64+l)*8+j <-> W[roff+32ks+8(l>>4)+j][16nt+(l&15)]
// Block 7 (phase2-B map): row = 32ks + 16*(j>>2) + 4*(l>>4) + (j&3). Tail range zeroes cnt.
__global__ __launch_bounds__(256) void prep_kernel(
    const float* __restrict__ We1, const float* __restrict__ We2,
    const float* __restrict__ Wn1, const float* __restrict__ Wn2,
    const float* __restrict__ be1, const float* __restrict__ be2,
    const float* __restrict__ ge,  const float* __restrict__ bge,
    const float* __restrict__ bn1, const float* __restrict__ bn2,
    const float* __restrict__ gn,  const float* __restrict__ bgn,
    short* __restrict__ wf, float* __restrict__ bf, int* __restrict__ cnt)
{
  int t = blockIdx.x*256 + threadIdx.x;
  if (t < WF_TOTAL) {
    int blk = t >> 14, u = t & 16383;
    int j = u & 7, l = (u>>3)&63, nt = (u>>9)&7, ks = u>>12;
    const float* src; int roff; bool blayout = false;
    switch (blk) {
      case 0: src = We1; roff = 0;   break;
      case 1: src = We1; roff = 128; break;
      case 2: src = We1; roff = 256; break;
      case 3: src = We2; roff = 0;   break;
      case 4: src = Wn1; roff = 0;   break;
      case 5: src = Wn1; roff = 128; break;
      case 6: src = Wn2; roff = 0;   break;
      default: src = We2; roff = 0; blayout = true; break;
    }
    int row = blayout ? (32*ks + 16*(j>>2) + 4*(l>>4) + (j&3))
                      : (roff + 32*ks + 8*(l>>4) + j);
    int col = 16*nt + (l&15);
    wf[t] = f2bf(src[row*H + col]);
  } else if (t < WF_TOTAL + BIASF_FLOATS) {
    int tb = t - WF_TOTAL;
    int arr = tb >> 11, u = tb & 2047;
    int r = u&3, l = (u>>2)&63, mt = u>>8;
    int feat = 16*mt + 4*(l>>4) + r;
    const float* s;
    switch (arr) {
      case 0: s = be1; break; case 1: s = be2; break;
      case 2: s = ge;  break; case 3: s = bge; break;
      case 4: s = bn1; break; case 5: s = bn2; break;
      case 6: s = gn;  break; default: s = bgn; break;
    }
    bf[tb] = s[feat];
  } else if (t < PREP_TOTAL) {
    cnt[t - WF_TOTAL - BIASF_FLOATS] = 0;
  }
}

// ---------- CSR build ----------
__global__ __launch_bounds__(256) void hist_kernel(const int* __restrict__ ei, int* __restrict__ cnt){
  int e = blockIdx.x*256 + threadIdx.x;
  if (e < NE) atomicAdd(&cnt[ei[2*e+1]], 1);
}

__global__ __launch_bounds__(256) void scan1_kernel(const int* __restrict__ cnt,
                                                    int* __restrict__ tmp, int* __restrict__ blocksum){
  __shared__ int s[256];
  int t = threadIdx.x, i = blockIdx.x*256 + t;
  int v = (i < NN) ? cnt[i] : 0;
  s[t] = v; __syncthreads();
#pragma unroll
  for (int o=1; o<256; o<<=1){
    int u = (t >= o) ? s[t-o] : 0;
    __syncthreads();
    s[t] += u;
    __syncthreads();
  }
  if (i < NN) tmp[i] = s[t];
  if (t == 255) blocksum[blockIdx.x] = s[255];
}

// scan2 folded in: every block computes its own exclusive prefix over blocksum[0..bid)
__global__ __launch_bounds__(256) void scan3_kernel(const int* __restrict__ cnt, const int* __restrict__ tmp,
                                                    const int* __restrict__ blocksum,
                                                    int* __restrict__ rowstart, int* __restrict__ cursor){
  __shared__ int pfx;
  int t = threadIdx.x, bid = blockIdx.x;
  if (t < 64){
    int p = 0;
    for (int k = t; k < bid; k += 64) p += blocksum[k];
#pragma unroll
    for (int o=32; o>0; o>>=1) p += __shfl_down(p, o);
    if (t == 0) pfx = p;
  }
  __syncthreads();
  int i = bid*256 + t;
  if (i < NN){
    int rs = tmp[i] - cnt[i] + pfx;
    rowstart[i] = rs; cursor[i] = rs;
  }
}

__global__ __launch_bounds__(256) void scatter_kernel(const int* __restrict__ ei,
                                                      int* __restrict__ cursor, int* __restrict__ csr){
  int e = blockIdx.x*256 + threadIdx.x;
  if (e < NE){
    int r = ei[2*e+1];
    int p = atomicAdd(&cursor[r], 1);
    csr[p] = e;
  }
}

// 2 nodes per wave (half-wave each, float4/lane), 8 gathers in flight, dual accumulators
__global__ __launch_bounds__(256) void segsum_kernel(const int* __restrict__ csr,
                                                     const int* __restrict__ rowstart,
                                                     const int* __restrict__ cnt,
                                                     const float* __restrict__ edge_feats,
                                                     float* __restrict__ acc){
  int tid = threadIdx.x;
  int w = tid>>6, l = tid&63;
  int hh = l>>5, q = l&31;
  int n = blockIdx.x*8 + w*2 + hh;
  if (n >= NN) return;
  int start = rowstart[n], deg = cnt[n];
  floatx4 s0 = floatx4{0.f,0.f,0.f,0.f};
  floatx4 s1 = floatx4{0.f,0.f,0.f,0.f};
  int k = 0;
  for (; k+8 <= deg; k += 8){
    int e0 = csr[start+k],   e1 = csr[start+k+1];
    int e2 = csr[start+k+2], e3 = csr[start+k+3];
    int e4 = csr[start+k+4], e5 = csr[start+k+5];
    int e6 = csr[start+k+6], e7 = csr[start+k+7];
    floatx4 v0 = *(const floatx4*)(edge_feats + (size_t)e0*H + 4*q);
    floatx4 v1 = *(const floatx4*)(edge_feats + (size_t)e1*H + 4*q);
    floatx4 v2 = *(const floatx4*)(edge_feats + (size_t)e2*H + 4*q);
    floatx4 v3 = *(const floatx4*)(edge_feats + (size_t)e3*H + 4*q);
    floatx4 v4 = *(const floatx4*)(edge_feats + (size_t)e4*H + 4*q);
    floatx4 v5 = *(const floatx4*)(edge_feats + (size_t)e5*H + 4*q);
    floatx4 v6 = *(const floatx4*)(edge_feats + (size_t)e6*H + 4*q);
    floatx4 v7 = *(const floatx4*)(edge_feats + (size_t)e7*H + 4*q);
    s0 += v0; s1 += v1; s0 += v2; s1 += v3;
    s0 += v4; s1 += v5; s0 += v6; s1 += v7;
  }
  for (; k+4 <= deg; k += 4){
    int e0 = csr[start+k],   e1 = csr[start+k+1];
    int e2 = csr[start+k+2], e3 = csr[start+k+3];
    floatx4 v0 = *(const floatx4*)(edge_feats + (size_t)e0*H + 4*q);
    floatx4 v1 = *(const floatx4*)(edge_feats + (size_t)e1*H + 4*q);
    floatx4 v2 = *(const floatx4*)(edge_feats + (size_t)e2*H + 4*q);
    floatx4 v3 = *(const floatx4*)(edge_feats + (size_t)e3*H + 4*q);
    s0 += v0; s1 += v1; s0 += v2; s1 += v3;
  }
  for (; k < deg; ++k){
    int e = csr[start+k];
    s0 += *(const floatx4*)(edge_feats + (size_t)e*H + 4*q);
  }
  s0 += s1;
  *(floatx4*)(acc + (size_t)n*H + 4*q) = s0;
}

// ---------- P projections: Ps = nf@W_s + be1 (bias folded), Pr = nf@W_r ----------
__global__ __launch_bounds__(256) void pproj_kernel(
    const float* __restrict__ node_feats,
    const short* __restrict__ wsf, const short* __restrict__ wrf,
    const float* __restrict__ b1f,
    short* __restrict__ Ps, short* __restrict__ Pr)
{
  const int tid = threadIdx.x;
  const int w = tid>>6, l = tid&63, g = l>>4, lo = l&15;
  int row = blockIdx.x*64 + w*16 + lo;
  bool valid = row < NN;
  int rowc = valid ? row : (NN-1);
  const float* sp = node_feats + (size_t)rowc*H;

  short8 ein[4];
#pragma unroll
  for (int ks=0; ks<4; ++ks){
    const int koff = ks*32 + g*8;
    floatx4 f0 = *(const floatx4*)(sp + koff);
    floatx4 f1 = *(const floatx4*)(sp + koff + 4);
    ein[ks][0]=f2bf(f0[0]); ein[ks][1]=f2bf(f0[1]); ein[ks][2]=f2bf(f0[2]); ein[ks][3]=f2bf(f0[3]);
    ein[ks][4]=f2bf(f1[0]); ein[ks][5]=f2bf(f1[1]); ein[ks][6]=f2bf(f1[2]); ein[ks][7]=f2bf(f1[3]);
  }

  floatx4 as[8], ar[8];
#pragma unroll
  for (int mt=0; mt<8; ++mt){ as[mt] = floatx4{0,0,0,0}; ar[mt] = floatx4{0,0,0,0}; }
#pragma unroll
  for (int ks=0; ks<4; ++ks){
#pragma unroll
    for (int mt=0; mt<8; ++mt){
      short8 wv = *(const short8*)(wsf + ((ks*8+mt)*64 + l)*8);
      as[mt] = __builtin_amdgcn_mfma_f32_16x16x32_bf16(wv, ein[ks], as[mt], 0,0,0);
      short8 wv2 = *(const short8*)(wrf + ((ks*8+mt)*64 + l)*8);
      ar[mt] = __builtin_amdgcn_mfma_f32_16x16x32_bf16(wv2, ein[ks], ar[mt], 0,0,0);
    }
  }

  if (valid){
    short* ps = Ps + (size_t)rowc*H + g*32;
    short* pr = Pr + (size_t)rowc*H + g*32;
#pragma unroll
    for (int mt=0; mt<8; ++mt){
      floatx4 bv = *(const floatx4*)(b1f + (mt*64+l)*4);
      short4v vs, vr;
#pragma unroll
      for (int r=0; r<4; ++r){ vs[r] = f2bf(as[mt][r] + bv[r]); vr[r] = f2bf(ar[mt][r]); }
      *(short4v*)(ps + mt*4) = vs;
      *(short4v*)(pr + mt*4) = vr;
    }
  }
}

// ---------- edge kernel (converged config): 512 threads, 64KB LDS weights,
// in-register phase1->phase2 hand-off, R=2, 1-deep ef + P-gather pipelines. VGPR ~72.
template<int R>
__global__ __launch_bounds__(512) void edge_kernel(
    const int* __restrict__ edge_idx,
    const float* __restrict__ edge_feats,
    const short* __restrict__ Ps, const short* __restrict__ Pr,
    const short* __restrict__ wef, const short* __restrict__ w2fB,
    const float* __restrict__ b2f,
    const float* __restrict__ gf,  const float* __restrict__ bgf,
    float* __restrict__ out_edge)
{
  extern __shared__ short smem[];
  short* wA = smem;              // wef:  16384 shorts (32KB)
  short* wB = smem + 16384;      // w2fB: 16384 shorts (32KB)
  const int tid = threadIdx.x;
  const int w = tid>>6, l = tid&63, g = l>>4, lo = l&15;

  int rowc[R]; bool valid[R]; int2 se[R];
#pragma unroll
  for (int b=0; b<R; ++b){
    int row = blockIdx.x*(8*16*R) + w*(16*R) + b*16 + lo;
    valid[b] = row < NE;
    rowc[b]  = valid[b] ? row : (NE-1);
    se[b] = *(const int2*)(edge_idx + 2*rowc[b]);
  }

  // stage weights: 4 rounds x 512 threads x 16B per matrix
#pragma unroll
  for (int rnd=0; rnd<4; ++rnd){
    int o = (rnd*512 + tid)*8;
    *(short8*)(wA + o) = *(const short8*)(wef  + o);
    *(short8*)(wB + o) = *(const short8*)(w2fB + o);
  }

  // prefetch batch-0 P gathers + batch-0 full ef row (10 loads in flight under staging)
  short8 vs[4], vr[4];
  {
    const short* ps = Ps + (size_t)se[0].x*H + g*32;
    const short* pr = Pr + (size_t)se[0].y*H + g*32;
#pragma unroll
    for (int m2=0; m2<4; ++m2){
      vs[m2] = *(const short8*)(ps + m2*8);
      vr[m2] = *(const short8*)(pr + m2*8);
    }
  }
  floatx4 ef[8];
  {
    const float* sp = edge_feats + (size_t)rowc[0]*H;
#pragma unroll
    for (int ks=0; ks<4; ++ks){
      ef[2*ks]   = *(const floatx4*)(sp + ks*32 + g*8);
      ef[2*ks+1] = *(const floatx4*)(sp + ks*32 + g*8 + 4);
    }
  }
  __syncthreads();

#pragma unroll
  for (int b=0; b<R; ++b){
    // convert current ef -> bf16 fragments (frees ef registers)
    short8 ein[4];
#pragma unroll
    for (int ks=0; ks<4; ++ks){
      ein[ks][0]=f2bf(ef[2*ks][0]);   ein[ks][1]=f2bf(ef[2*ks][1]);
      ein[ks][2]=f2bf(ef[2*ks][2]);   ein[ks][3]=f2bf(ef[2*ks][3]);
      ein[ks][4]=f2bf(ef[2*ks+1][0]); ein[ks][5]=f2bf(ef[2*ks+1][1]);
      ein[ks][6]=f2bf(ef[2*ks+1][2]); ein[ks][7]=f2bf(ef[2*ks+1][3]);
    }

    // issue next batch's full-row ef loads (hide under this batch's MFMA)
    if (b+1 < R){
      const float* sp = edge_feats + (size_t)rowc[b+1]*H;
#pragma unroll
      for (int ks=0; ks<4; ++ks){
        ef[2*ks]   = *(const floatx4*)(sp + ks*32 + g*8);
        ef[2*ks+1] = *(const floatx4*)(sp + ks*32 + g*8 + 4);
      }
    }

    // ---- phase 1: ef @ W_e (weights from LDS) ----
    floatx4 acc[8];
#pragma unroll
    for (int mt=0; mt<8; ++mt) acc[mt] = floatx4{0.f,0.f,0.f,0.f};
#pragma unroll
    for (int ks=0; ks<4; ++ks){
#pragma unroll
      for (int mt=0; mt<8; ++mt){
        short8 wv = *(const short8*)(wA + ((ks*8+mt)*64 + l)*8);   // ds_read_b128
        acc[mt] = __builtin_amdgcn_mfma_f32_16x16x32_bf16(wv, ein[ks], acc[mt], 0,0,0);
      }
    }

    // consume gathers: add Ps[snd] (incl. be1) + Pr[rcv]
#pragma unroll
    for (int m2=0; m2<4; ++m2)
#pragma unroll
      for (int r=0; r<4; ++r){
        acc[2*m2][r]   += bf2f(vs[m2][r])   + bf2f(vr[m2][r]);
        acc[2*m2+1][r] += bf2f(vs[m2][4+r]) + bf2f(vr[m2][4+r]);
      }

    // issue next batch's gathers (hidden under this batch's phase2 + LN)
    if (b+1 < R){
      const short* ps = Ps + (size_t)se[b+1].x*H + g*32;
      const short* pr = Pr + (size_t)se[b+1].y*H + g*32;
#pragma unroll
      for (int m2=0; m2<4; ++m2){
        vs[m2] = *(const short8*)(ps + m2*8);
        vr[m2] = *(const short8*)(pr + m2*8);
      }
    }

    // relu + pack straight into phase-2 B-fragments (in-register hand-off)
    short8 hb[4];
#pragma unroll
    for (int s=0; s<4; ++s){
#pragma unroll
      for (int r=0; r<4; ++r){
        float v0 = acc[2*s][r];
        float v1 = acc[2*s+1][r];
        hb[s][r]   = f2bf(v0 > 0.f ? v0 : 0.f);
        hb[s][4+r] = f2bf(v1 > 0.f ? v1 : 0.f);
      }
    }

    // ---- phase 2: y^T = W2^T @ h^T (+b2 via acc init) ----
#pragma unroll
    for (int mt=0; mt<8; ++mt) acc[mt] = *(const floatx4*)(b2f + (mt*64+l)*4);
#pragma unroll
    for (int s=0; s<4; ++s){
#pragma unroll
      for (int mt=0; mt<8; ++mt){
        short8 wv = *(const short8*)(wB + ((s*8+mt)*64 + l)*8);   // ds_read_b128
        acc[mt] = __builtin_amdgcn_mfma_f32_16x16x32_bf16(wv, hb[s], acc[mt], 0,0,0);
      }
    }

    // ---- LayerNorm + residual + store ----
    float sum = 0.f, ssq = 0.f;
#pragma unroll
    for (int mt=0; mt<8; ++mt)
#pragma unroll
      for (int r=0; r<4; ++r){ float v = acc[mt][r]; sum += v; ssq += v*v; }
    sum += __shfl_xor(sum, 16); ssq += __shfl_xor(ssq, 16);
    sum += __shfl_xor(sum, 32); ssq += __shfl_xor(ssq, 32);
    const float mean = sum * (1.f/H);
    const float var  = ssq * (1.f/H) - mean*mean;
    const float rs   = rsqrtf(var + 1e-5f);

    const float* resid = edge_feats + (size_t)rowc[b]*H;
    float* outp = out_edge + (size_t)rowc[b]*H;
#pragma unroll
    for (int mt=0; mt<8; ++mt){
      floatx4 gv  = *(const floatx4*)(gf  + (mt*64+l)*4);
      floatx4 bgv = *(const floatx4*)(bgf + (mt*64+l)*4);
      floatx4 efr = *(const floatx4*)(resid + mt*16 + g*4);
      floatx4 o;
#pragma unroll
      for (int r=0; r<4; ++r) o[r] = efr[r] + (acc[mt][r]-mean)*rs*gv[r] + bgv[r];
      if (valid[b]) *(floatx4*)(outp + mt*16 + g*4) = o;
    }
  }
}

// ---------- node kernel (unchanged, validated; uses old-layout blocks 4/5/6) ----------
__global__ __launch_bounds__(256) void node_kernel(
    const float* __restrict__ node_feats,
    const short* __restrict__ w1f, const short* __restrict__ w2f,
    const float* __restrict__ b1f, const float* __restrict__ b2f,
    const float* __restrict__ gf,  const float* __restrict__ bgf,
    float* __restrict__ out_node)
{
  __shared__ short lds_h[4*2048];
  const int tid = threadIdx.x;
  const int w = tid>>6, l = tid&63, g = l>>4, lo = l&15;
  short* ldsw = lds_h + w*2048;

  int row = blockIdx.x*64 + w*16 + lo;
  bool valid = row < NN;
  int rowc = valid ? row : (NN-1);
  const float* sp0 = node_feats + (size_t)rowc*H;
  const float* sp1 = out_node   + (size_t)rowc*H;   // segsum acc

  floatx4 acc1[8];
#pragma unroll
  for (int mt=0; mt<8; ++mt) acc1[mt] = *(const floatx4*)(b1f + (mt*64+l)*4);

#pragma unroll
  for (int ks=0; ks<8; ++ks){
    const float* sp = (ks<4) ? sp0 : sp1;
    const int koff = (ks&3)*32 + g*8;
    floatx4 f0 = *(const floatx4*)(sp + koff);
    floatx4 f1 = *(const floatx4*)(sp + koff + 4);
    short8 ein;
    ein[0]=f2bf(f0[0]); ein[1]=f2bf(f0[1]); ein[2]=f2bf(f0[2]); ein[3]=f2bf(f0[3]);
    ein[4]=f2bf(f1[0]); ein[5]=f2bf(f1[1]); ein[6]=f2bf(f1[2]); ein[7]=f2bf(f1[3]);
#pragma unroll
    for (int mt=0; mt<8; ++mt){
      short8 wv = *(const short8*)(w1f + ((ks*8+mt)*64 + l)*8);
      acc1[mt] = __builtin_amdgcn_mfma_f32_16x16x32_bf16(wv, ein, acc1[mt], 0,0,0);
    }
  }

#pragma unroll
  for (int mt=0; mt<8; ++mt){
    short4v hv;
#pragma unroll
    for (int r=0; r<4; ++r){
      float v = acc1[mt][r];
      hv[r] = f2bf(v > 0.f ? v : 0.f);
    }
    int off = (lo*256 + mt*32 + g*8) ^ ((lo&7)<<4);
    *(short4v*)((char*)ldsw + off) = hv;
  }

  floatx4 acc2[8];
#pragma unroll
  for (int mt=0; mt<8; ++mt) acc2[mt] = *(const floatx4*)(b2f + (mt*64+l)*4);

#pragma unroll
  for (int s=0; s<4; ++s){
    int roff = (lo*256 + s*64 + g*16) ^ ((lo&7)<<4);
    short8 hb = *(const short8*)((char*)ldsw + roff);
#pragma unroll
    for (int mt=0; mt<8; ++mt){
      short8 wv = *(const short8*)(w2f + ((s*8+mt)*64 + l)*8);
      acc2[mt] = __builtin_amdgcn_mfma_f32_16x16x32_bf16(wv, hb, acc2[mt], 0,0,0);
    }
  }

  float sum = 0.f, ssq = 0.f;
#pragma unroll
  for (int mt=0; mt<8; ++mt)
#pragma unroll
    for (int r=0; r<4; ++r){ float v = acc2[mt][r]; sum += v; ssq += v*v; }
  sum += __shfl_xor(sum, 16); ssq += __shfl_xor(ssq, 16);
  sum += __shfl_xor(sum, 32); ssq += __shfl_xor(ssq, 32);
  const float mean = sum * (1.f/H);
  const float var  = ssq * (1.f/H) - mean*mean;
  const float rs   = rsqrtf(var + 1e-5f);

#pragma unroll
  for (int mt=0; mt<8; ++mt){
    floatx4 gv  = *(const floatx4*)(gf  + (mt*64+l)*4);
    floatx4 bgv = *(const floatx4*)(bgf + (mt*64+l)*4);
    floatx4 nf  = *(const floatx4*)(node_feats + (size_t)rowc*H + mt*16 + g*4);
    floatx4 o;
#pragma unroll
    for (int r=0; r<4; ++r) o[r] = nf[r] + (acc2[mt][r]-mean)*rs*gv[r] + bgv[r];
    if (valid) *(floatx4*)(out_node + (size_t)rowc*H + mt*16 + g*4) = o;
  }
}

extern "C" void kernel_launch(void* const* d_in, const int* in_sizes, int n_in,
                              void* d_out, int out_size, void* d_ws, size_t ws_size,
                              hipStream_t stream)
{
  const int*   edge_idx   = (const int*)  d_in[0];
  const float* node_feats = (const float*)d_in[1];
  const float* edge_feats = (const float*)d_in[2];
  const float* We1=(const float*)d_in[3];  const float* be1=(const float*)d_in[4];
  const float* We2=(const float*)d_in[5];  const float* be2=(const float*)d_in[6];
  const float* ge =(const float*)d_in[7];  const float* bge=(const float*)d_in[8];
  const float* Wn1=(const float*)d_in[9];  const float* bn1=(const float*)d_in[10];
  const float* Wn2=(const float*)d_in[11]; const float* bn2=(const float*)d_in[12];
  const float* gn =(const float*)d_in[13]; const float* bgn=(const float*)d_in[14];

  float* out_node = (float*)d_out;                    // doubles as segsum acc
  float* out_edge = out_node + (size_t)NN*H;

  char* ws = (char*)d_ws;
  short* wf      = (short*)ws;
  float* bf      = (float*)(ws + OFF_BF);
  short* Ps      = (short*)(ws + OFF_PS);
  short* Pr      = (short*)(ws + OFF_PR);
  int* cnt       = (int*)(ws + OFF_CNT);
  int* tmp       = (int*)(ws + OFF_TMP);
  int* rowstart  = (int*)(ws + OFF_RS);
  int* cursor    = (int*)(ws + OFF_CUR);
  int* blocksum  = (int*)(ws + OFF_BSUM);
  int* csr       = (int*)(ws + OFF_CSR);

  short* wsf  = wf;                 // We1 rows 0-127
  short* wrf  = wf + 16384;         // We1 rows 128-255
  short* wef  = wf + 32768;         // We1 rows 256-383
  short* wn1f = wf + 65536;         // Wn1 (8 ks, blocks 4+5)
  short* wn2f = wf + 98304;         // Wn2 (block 6)
  short* w2fB = wf + 114688;        // We2, phase2-B layout (block 7)
  float* b1f  = bf;         float* b2f  = bf + 2048;
  float* gef  = bf + 4096;  float* bgef = bf + 6144;
  float* bn1f = bf + 8192;  float* bn2f = bf + 10240;
  float* gnf  = bf + 12288; float* bgnf = bf + 14336;

  // prep (weights+biases) + cnt zeroing, one launch
  prep_kernel<<<(PREP_TOTAL + 255)/256, 256, 0, stream>>>(
      We1, We2, Wn1, Wn2, be1, be2, ge, bge, bn1, bn2, gn, bgn, wf, bf, cnt);

  // CSR build (scan2 folded into scan3)
  hist_kernel<<<(NE+255)/256, 256, 0, stream>>>(edge_idx, cnt);
  scan1_kernel<<<NB1, 256, 0, stream>>>(cnt, tmp, blocksum);
  scan3_kernel<<<NB1, 256, 0, stream>>>(cnt, tmp, blocksum, rowstart, cursor);
  scatter_kernel<<<(NE+255)/256, 256, 0, stream>>>(edge_idx, cursor, csr);

  // node projections for edge phase-1 (Ps = nf@W_s + be1, Pr = nf@W_r)
  pproj_kernel<<<(NN+63)/64, 256, 0, stream>>>(node_feats, wsf, wrf, b1f, Ps, Pr);

  // edge MLP: 512-thread blocks, 64KB LDS weights, R=2 (converged config, VGPR~72)
  edge_kernel<2><<<(NE + 255)/256, 512, 65536, stream>>>(
      edge_idx, edge_feats, Ps, Pr, wef, w2fB, b2f, gef, bgef, out_edge);

  // segment_sum into out_node (acc), then node MLP consumes + overwrites
  segsum_kernel<<<(NN+7)/8, 256, 0, stream>>>(csr, rowstart, cnt, edge_feats, out_node);

  node_kernel<<<(NN+63)/64, 256, 0, stream>>>(
      node_feats, wn1f, wn2f, bn1f, bn2f, gnf, bgnf, out_node);
}